// Round 13
// baseline (73.353 us; speedup 1.0000x reference)
//
#include <hip/hip_runtime.h>
#include <stdint.h>

#define B_N    16384
#define F_N    512
#define NPAIR  128            // 256 steps (1 pad + 255 sites) fused into 128 pairs per side
#define CHUNKP 8              // pairs per staged chunk
#define NCHUNK (NPAIR/CHUNKP)

typedef float    f32x4  __attribute__((ext_vector_type(4)));
typedef short    s16x4  __attribute__((ext_vector_type(4)));
typedef short    s16x8  __attribute__((ext_vector_type(8)));
typedef int      i32x2  __attribute__((ext_vector_type(2)));
typedef _Float16 f16x4  __attribute__((ext_vector_type(4)));

// ws layout (shorts): left pair-frags [0,262144), right [262144,524288),
// M (256 f32) at short 524288, c0 at short 524800.
// per pair-side: 2048 shorts = 4 regions x 512:
//   rg0 = [P00hi|P10hi] per lane, rg1 = [P01hi|P11hi], rg2 = [P00lo|P10lo], rg3 = [P01lo|P11lo]
#define WS_SIDE_STRIDE 262144
#define WS_BYTES_NEEDED ((524800 + 2) * 2)

// ---- K=16 MFMA selection (bf16 preferred, f16 fallback; prep dtype must match) ----
#if __has_builtin(__builtin_amdgcn_mfma_f32_16x16x16bf16_1k)
#define AMODE_BF16 1
static __device__ __forceinline__ f32x4 MFMA16(s16x4 a, s16x4 b, f32x4 c) {
  return __builtin_amdgcn_mfma_f32_16x16x16bf16_1k(a, b, c, 0, 0, 0);
}
#elif __has_builtin(__builtin_amdgcn_mfma_f32_16x16x16_bf16)
#define AMODE_BF16 1
static __device__ __forceinline__ f32x4 MFMA16(s16x4 a, s16x4 b, f32x4 c) {
  return __builtin_amdgcn_mfma_f32_16x16x16_bf16(a, b, c, 0, 0, 0);
}
#else
#define AMODE_BF16 0
static __device__ __forceinline__ f32x4 MFMA16(s16x4 a, s16x4 b, f32x4 c) {
  return __builtin_amdgcn_mfma_f32_16x16x16f16(__builtin_bit_cast(f16x4, a),
                                               __builtin_bit_cast(f16x4, b), c, 0, 0, 0);
}
#endif

// element split: w -> hi + lo in the selected 16-bit dtype (hi truncated, lo exact remainder)
static __device__ __forceinline__ void cvt_split(float w, unsigned short &hi, unsigned short &lo) {
#if AMODE_BF16
  unsigned u = __float_as_uint(w);
  hi = (unsigned short)(u >> 16);
  float rl = w - __uint_as_float((unsigned)hi << 16);
  lo = (unsigned short)(__float_as_uint(rl) >> 16);
#else
  _Float16 h = (_Float16)w;
  hi = __builtin_bit_cast(unsigned short, h);
  _Float16 l = (_Float16)(w - (float)h);
  lo = __builtin_bit_cast(unsigned short, l);
#endif
}

// 4 f32 states -> B operands (k = 4g+i maps directly to st[i]; no cross-lane moves)
static __device__ __forceinline__ void splitB(const float* st, s16x4 &Bh, s16x4 &Bl) {
#if AMODE_BF16
  unsigned ph0 = __builtin_amdgcn_perm(__float_as_uint(st[1]), __float_as_uint(st[0]), 0x07060302u);
  unsigned ph1 = __builtin_amdgcn_perm(__float_as_uint(st[3]), __float_as_uint(st[2]), 0x07060302u);
  float l0 = st[0] - __uint_as_float(__float_as_uint(st[0]) & 0xffff0000u);
  float l1 = st[1] - __uint_as_float(__float_as_uint(st[1]) & 0xffff0000u);
  float l2 = st[2] - __uint_as_float(__float_as_uint(st[2]) & 0xffff0000u);
  float l3 = st[3] - __uint_as_float(__float_as_uint(st[3]) & 0xffff0000u);
  unsigned pl0 = __builtin_amdgcn_perm(__float_as_uint(l1), __float_as_uint(l0), 0x07060302u);
  unsigned pl1 = __builtin_amdgcn_perm(__float_as_uint(l3), __float_as_uint(l2), 0x07060302u);
  i32x2 h; h.x = (int)ph0; h.y = (int)ph1;
  i32x2 l; l.x = (int)pl0; l.y = (int)pl1;
  Bh = __builtin_bit_cast(s16x4, h);
  Bl = __builtin_bit_cast(s16x4, l);
#else
  _Float16 h0 = (_Float16)st[0], h1 = (_Float16)st[1], h2 = (_Float16)st[2], h3 = (_Float16)st[3];
  f16x4 H = {h0, h1, h2, h3};
  f16x4 L = {(_Float16)(st[0] - (float)h0), (_Float16)(st[1] - (float)h1),
             (_Float16)(st[2] - (float)h2), (_Float16)(st[3] - (float)h3)};
  Bh = __builtin_bit_cast(s16x4, H);
  Bl = __builtin_bit_cast(s16x4, L);
#endif
}

static __device__ __forceinline__ s16x4 lo4(s16x8 v) {
  return __builtin_shufflevector(v, v, 0, 1, 2, 3);
}
static __device__ __forceinline__ s16x4 hi4(s16x8 v) {
  return __builtin_shufflevector(v, v, 4, 5, 6, 7);
}

// ---------------- prep: fuse site pairs, emit K=16 MFMA A-frags (natural layout) ------
// (byte-identical to round 10/12 — verified correct, absmax 0.125)
__global__ __launch_bounds__(256) void mps_prep(
    const float* __restrict__ W0, const float* __restrict__ W_left,
    const float* __restrict__ W_out, const float* __restrict__ W_right,
    const float* __restrict__ WN, const float* __restrict__ d1_w,
    const float* __restrict__ d1_b, const float* __restrict__ d2_w,
    const float* __restrict__ d2_b, unsigned short* __restrict__ ws)
{
  int bid = blockIdx.x;
  if (bid < 256) {
    int side = bid >> 7;
    int pair = bid & 127;
    __shared__ float Wa[512];     // [d*32 + p*16 + e]
    __shared__ float Wb[512];
    __shared__ float Amat[4][256]; // [i*2+j][m*16+k]
    int t = threadIdx.x;
    bool pad_a = (pair == 0);
    const float* base_a = side ? (W_right + (size_t)(255 - 2*pair) * 512)
                               : (W_left  + (size_t)(2*pair - 1) * 512);
    const float* base_b = side ? (W_right + (size_t)(254 - 2*pair) * 512)
                               : (W_left  + (size_t)(2*pair) * 512);
#pragma unroll
    for (int e = t; e < 512; e += 256) {
      float va;
      if (pad_a) { int d = e >> 5, p = (e >> 4) & 1, m = e & 15; va = (p == 0 && d == m) ? 1.f : 0.f; }
      else va = base_a[e];
      Wa[e] = va;
      Wb[e] = base_b[e];
    }
    __syncthreads();
#pragma unroll
    for (int ei = t; ei < 1024; ei += 256) {
      int ij = ei >> 8;            // i*2 + j
      int i_ = ij >> 1, j_ = ij & 1;
      int rem = ei & 255;
      int m = rem >> 4, k = rem & 15;
      float acc = 0.f;
      if (side == 0) {
#pragma unroll
        for (int tt = 0; tt < 16; ++tt) acc += Wa[k*32 + i_*16 + tt] * Wb[tt*32 + j_*16 + m];
      } else {
#pragma unroll
        for (int tt = 0; tt < 16; ++tt) acc += Wb[m*32 + j_*16 + tt] * Wa[tt*32 + i_*16 + k];
      }
      Amat[ij][m*16 + k] = acc;
    }
    __syncthreads();
    {
      int rg = t >> 6, l = t & 63;      // rg: 0=[00h|10h] 1=[01h|11h] 2=[00l|10l] 3=[01l|11l]
      int jj = rg & 1, lo = rg >> 1;
      int m = l & 15, g4 = (l >> 4) * 4;
      s16x8 v8;
#pragma unroll
      for (int i = 0; i < 4; ++i) {
        int k = g4 + i;
        unsigned short h, lw;
        cvt_split(Amat[jj][m*16 + k], h, lw);          // (i=0, j=jj)
        v8[i] = (short)(lo ? lw : h);
        cvt_split(Amat[2 + jj][m*16 + k], h, lw);      // (i=1, j=jj)
        v8[4 + i] = (short)(lo ? lw : h);
      }
      *reinterpret_cast<s16x8*>(ws + (size_t)side * WS_SIDE_STRIDE
                                   + (size_t)pair * 2048 + rg * 512 + l * 8) = v8;
    }
  } else {
    // M[d][e] = sum_o wef[o] * W_out[d][o][e];  c0 = d2_b + sum_h d2_w[h] d1_b[h]
    int t = threadIdx.x;
    int d = t >> 4, e = t & 15;
    float acc = 0.f;
#pragma unroll
    for (int o = 0; o < 8; ++o) {
      float wef = 0.f;
      for (int hh = 0; hh < 24; ++hh) wef += d2_w[hh] * d1_w[hh*8 + o];
      acc += wef * W_out[d*128 + o*16 + e];
    }
    float* wf = reinterpret_cast<float*>(ws);
    wf[262144 + t] = acc;
    if (t == 0) {
      float c0 = d2_b[0];
      for (int hh = 0; hh < 24; ++hh) c0 += d2_w[hh] * d1_b[hh];
      wf[262400] = c0;
    }
  }
}

// ---------------- main: 256 blocks x 8 waves {4L,4R}, 16 samples/wave, 2 waves/SIMD ----
// Latency-attack version: (1) bulk ds_read of 4 pairs' frags into registers behind a
// sched_barrier(0) fence (compiler cannot sink them to use sites — the R11/R12 failure);
// (2) all 12 MFMAs per pair are INDEPENDENT (C=0) — one MFMA latency on the serial path
// instead of a 3-deep accumulator chain; products summed in f32 VALU (same values,
// different association).
__global__ __launch_bounds__(512, 2) void mps_main(
    const float* __restrict__ x, const float* __restrict__ W0,
    const float* __restrict__ WN, const unsigned short* __restrict__ ws,
    float* __restrict__ out)
{
  __shared__ __align__(16) unsigned short sbuf[2][2][CHUNKP][4][64][8]; // 128 KiB
  __shared__ float fin[2][64][16];                                      // 8 KiB

  const int tidx = threadIdx.x;
  const int wave = tidx >> 6;
  const int lane = tidx & 63;
  const int side = wave >> 2;         // waves 0-3 left, 4-7 right
  const int q    = wave & 3;          // sample group
  const int n    = lane & 15;         // sample column
  const int g    = lane >> 4;         // lane group: rows/k 4g..4g+3
  const int b    = blockIdx.x * 64 + q * 16 + n;
  const float* xrow = x + (size_t)b * F_N;

  // init B: lane-group g holds v0[4g..4g+3]
  s16x4 Bh, Bl;
  float st[4];
  {
    float xi0 = side ? xrow[F_N-1] : xrow[0];
#pragma unroll
    for (int i = 0; i < 4; ++i) {
      int j = g*4 + i;
      float a0 = side ? WN[j*2]   : W0[j];
      float a1 = side ? WN[j*2+1] : W0[16+j];
      st[i] = fmaf(xi0, a1, a0);
    }
    splitB(st, Bh, Bl);
  }

  f32x4 Dz = {0.f, 0.f, 0.f, 0.f};

  // cooperative stage: 64 segments of 1 KB (2 sides x 8 pairs x 4 regions), 8 per wave
  auto stage = [&](int chunk, int db) {
#pragma unroll
    for (int s2 = 0; s2 < 8; ++s2) {
      int seg = wave * 8 + s2;
      int ss  = seg >> 5;
      int rem = seg & 31;
      int pr  = rem >> 2, rg = rem & 3;
      const unsigned short* src = ws + (size_t)ss * WS_SIDE_STRIDE
                                + (size_t)(chunk * CHUNKP + pr) * 2048 + rg * 512 + lane * 8;
      __builtin_amdgcn_global_load_lds(
        (const __attribute__((address_space(1))) void*)src,
        (__attribute__((address_space(3))) void*)(&sbuf[ss][db][pr][rg][0][0]),
        16, 0, 0);
    }
  };

  auto xbase = [&](int c) { return xrow + (side ? (496 - 16*c) : (16*c)); };

  float4 xq0, xq1, xq2, xq3;
  {
    const float* xp = xbase(0);
    xq0 = *reinterpret_cast<const float4*>(xp);
    xq1 = *reinterpret_cast<const float4*>(xp + 4);
    xq2 = *reinterpret_cast<const float4*>(xp + 8);
    xq3 = *reinterpret_cast<const float4*>(xp + 12);
  }

  stage(0, 0);
  asm volatile("s_waitcnt vmcnt(0)" ::: "memory");
  __syncthreads();

#pragma unroll 1
  for (int c = 0; c < NCHUNK; ++c) {
    float4 xn0 = xq0, xn1 = xq1, xn2 = xq2, xn3 = xq3;
    if (c + 1 < NCHUNK) {
      stage(c + 1, (c + 1) & 1);
      const float* xp = xbase(c + 1);
      xn0 = *reinterpret_cast<const float4*>(xp);
      xn1 = *reinterpret_cast<const float4*>(xp + 4);
      xn2 = *reinterpret_cast<const float4*>(xp + 8);
      xn3 = *reinterpret_cast<const float4*>(xp + 12);
    }
    const unsigned short* lb = &sbuf[side][c & 1][0][0][0][0];

    // x schedule for this chunk (elem i = xbase[i])
    float xa[8], xb[8];
    {
      float e0=xq0.x, e1=xq0.y, e2=xq0.z, e3=xq0.w, e4=xq1.x, e5=xq1.y, e6=xq1.z, e7=xq1.w;
      float e8=xq2.x, e9=xq2.y, e10=xq2.z, e11=xq2.w, e12=xq3.x, e13=xq3.y, e14=xq3.z, e15=xq3.w;
      if (side == 0) {
        xa[0]=e0;  xb[0]=e1;  xa[1]=e2;  xb[1]=e3;
        xa[2]=e4;  xb[2]=e5;  xa[3]=e6;  xb[3]=e7;
        xa[4]=e8;  xb[4]=e9;  xa[5]=e10; xb[5]=e11;
        xa[6]=e12; xb[6]=e13; xa[7]=e14; xb[7]=e15;
      } else {
        xa[0]=e15; xb[0]=e14; xa[1]=e13; xb[1]=e12;
        xa[2]=e11; xb[2]=e10; xa[3]=e9;  xb[3]=e8;
        xa[4]=e7;  xb[4]=e6;  xa[5]=e5;  xb[5]=e4;
        xa[6]=e3;  xb[6]=e2;  xa[7]=e1;  xb[7]=e0;
      }
    }

#pragma unroll
    for (int h2 = 0; h2 < 2; ++h2) {
      // -------- bulk register read: 4 pairs x 4 regions = 16 x ds_read_b128 --------
      s16x8 FR[4][4];
#pragma unroll
      for (int pp = 0; pp < 4; ++pp) {
#pragma unroll
        for (int rg = 0; rg < 4; ++rg) {
          FR[pp][rg] = *reinterpret_cast<const s16x8*>(
              lb + (h2*4 + pp)*2048 + rg*512 + lane*8);
        }
      }
      __builtin_amdgcn_sched_barrier(0);   // pin bulk loads above the compute

#pragma unroll
      for (int pp = 0; pp < 4; ++pp) {
        const int pr = h2*4 + pp;
        s16x4 a00h = lo4(FR[pp][0]), a10h = hi4(FR[pp][0]);
        s16x4 a01h = lo4(FR[pp][1]), a11h = hi4(FR[pp][1]);
        s16x4 a00l = lo4(FR[pp][2]), a10l = hi4(FR[pp][2]);
        s16x4 a01l = lo4(FR[pp][3]), a11l = hi4(FR[pp][3]);

        // 12 INDEPENDENT MFMAs (C = 0): one MFMA latency on the serial path
        f32x4 D00a = MFMA16(a00h, Bh, Dz);
        f32x4 D10a = MFMA16(a10h, Bh, Dz);
        f32x4 D01a = MFMA16(a01h, Bh, Dz);
        f32x4 D11a = MFMA16(a11h, Bh, Dz);
        f32x4 D00b = MFMA16(a00h, Bl, Dz);
        f32x4 D10b = MFMA16(a10h, Bl, Dz);
        f32x4 D01b = MFMA16(a01h, Bl, Dz);
        f32x4 D11b = MFMA16(a11h, Bl, Dz);
        f32x4 D00c = MFMA16(a00l, Bh, Dz);
        f32x4 D10c = MFMA16(a10l, Bh, Dz);
        f32x4 D01c = MFMA16(a01l, Bh, Dz);
        f32x4 D11c = MFMA16(a11l, Bh, Dz);

        // st = (S00 + xa S10) + xb (S01 + xa S11),  Sij = Dija + Dijb + Dijc (f32)
#pragma unroll
        for (int r = 0; r < 4; ++r) {
          float s00 = (D00a[r] + D00b[r]) + D00c[r];
          float s10 = (D10a[r] + D10b[r]) + D10c[r];
          float s01 = (D01a[r] + D01b[r]) + D01c[r];
          float s11 = (D11a[r] + D11b[r]) + D11c[r];
          float t0 = fmaf(xa[pr], s10, s00);
          float t1 = fmaf(xa[pr], s11, s01);
          st[r] = fmaf(xb[pr], t1, t0);
        }
        splitB(st, Bh, Bl);               // D-layout == next B-layout: no cross-lane moves
      }
    }
    asm volatile("s_waitcnt vmcnt(0)" ::: "memory");
    __syncthreads();
    xq0 = xn0; xq1 = xn1; xq2 = xn2; xq3 = xn3;
  }

  // final f32 state (natural rows 4g..4g+3) -> LDS
#pragma unroll
  for (int r = 0; r < 4; ++r) fin[side][q*16 + n][g*4 + r] = st[r];
  __syncthreads();

  // head: y = c0 + v^T M u, 8 threads per sample (64 samples x 8 = 512 threads)
  {
    int s = tidx >> 3, j = tidx & 7;
    const float* Mf = reinterpret_cast<const float*>(ws) + 262144;
    float c0 = reinterpret_cast<const float*>(ws)[262400];
    float acc = 0.f;
#pragma unroll
    for (int dd = 0; dd < 2; ++dd) {
      int d = j*2 + dd;
      float zd = 0.f;
#pragma unroll
      for (int e = 0; e < 16; ++e) zd = fmaf(Mf[d*16 + e], fin[1][s][e], zd);
      acc = fmaf(fin[0][s][d], zd, acc);
    }
    acc += __shfl_xor(acc, 1, 64);
    acc += __shfl_xor(acc, 2, 64);
    acc += __shfl_xor(acc, 4, 64);
    if (j == 0) out[blockIdx.x*64 + s] = acc + c0;
  }
}

extern "C" void kernel_launch(void* const* d_in, const int* in_sizes, int n_in,
                              void* d_out, int out_size, void* d_ws, size_t ws_size,
                              hipStream_t stream)
{
  const float* x       = (const float*)d_in[0];
  const float* W0      = (const float*)d_in[1];
  const float* W_left  = (const float*)d_in[2];
  const float* W_out   = (const float*)d_in[3];
  const float* W_right = (const float*)d_in[4];
  const float* WN      = (const float*)d_in[5];
  const float* d1_w    = (const float*)d_in[6];
  const float* d1_b    = (const float*)d_in[7];
  const float* d2_w    = (const float*)d_in[8];
  const float* d2_b    = (const float*)d_in[9];
  unsigned short* ws   = (unsigned short*)d_ws;
  float* out           = (float*)d_out;

  if (ws_size < (size_t)WS_BYTES_NEEDED) return;

  hipLaunchKernelGGL(mps_prep, dim3(257), dim3(256), 0, stream,
                     W0, W_left, W_out, W_right, WN, d1_w, d1_b, d2_w, d2_b, ws);
  hipLaunchKernelGGL(mps_main, dim3(B_N/64), dim3(512), 0, stream,
                     x, W0, WN, ws, out);
}

// Round 14
// 58.429 us; speedup vs baseline: 1.2554x; 1.2554x over previous
//
#include <hip/hip_runtime.h>
#include <stdint.h>

#define B_N    16384
#define F_N    512
#define NPAIR  128            // 256 steps (1 pad + 255 sites) fused into 128 pairs per side
#define CHUNKP 8              // pairs per staged chunk
#define NCHUNK (NPAIR/CHUNKP)

typedef float    f32x4  __attribute__((ext_vector_type(4)));
typedef short    s16x4  __attribute__((ext_vector_type(4)));
typedef short    s16x8  __attribute__((ext_vector_type(8)));
typedef int      i32x2  __attribute__((ext_vector_type(2)));
typedef _Float16 f16x4  __attribute__((ext_vector_type(4)));

typedef __attribute__((address_space(3))) const unsigned short* lds_cptr;

// compiler-proof LDS read: volatile asm cannot be sunk/deleted (R11/R12/R13 failure mode)
#define DSR(dst, base, offlit) \
  asm volatile("ds_read_b128 %0, %1 offset:" offlit : "=v"(dst) : "v"(base))

// ws layout (shorts): left pair-frags [0,262144), right [262144,524288),
// M (256 f32) at short 524288, c0 at short 524800.
// per pair-side: 2048 shorts = 4 regions x 512:
//   rg0 = [P00hi|P10hi] per lane, rg1 = [P01hi|P11hi], rg2 = [P00lo|P10lo], rg3 = [P01lo|P11lo]
#define WS_SIDE_STRIDE 262144
#define WS_BYTES_NEEDED ((524800 + 2) * 2)

// ---- K=16 MFMA selection (bf16 preferred, f16 fallback; prep dtype must match) ----
#if __has_builtin(__builtin_amdgcn_mfma_f32_16x16x16bf16_1k)
#define AMODE_BF16 1
static __device__ __forceinline__ f32x4 MFMA16(s16x4 a, s16x4 b, f32x4 c) {
  return __builtin_amdgcn_mfma_f32_16x16x16bf16_1k(a, b, c, 0, 0, 0);
}
#elif __has_builtin(__builtin_amdgcn_mfma_f32_16x16x16_bf16)
#define AMODE_BF16 1
static __device__ __forceinline__ f32x4 MFMA16(s16x4 a, s16x4 b, f32x4 c) {
  return __builtin_amdgcn_mfma_f32_16x16x16_bf16(a, b, c, 0, 0, 0);
}
#else
#define AMODE_BF16 0
static __device__ __forceinline__ f32x4 MFMA16(s16x4 a, s16x4 b, f32x4 c) {
  return __builtin_amdgcn_mfma_f32_16x16x16f16(__builtin_bit_cast(f16x4, a),
                                               __builtin_bit_cast(f16x4, b), c, 0, 0, 0);
}
#endif

// element split: w -> hi + lo in the selected 16-bit dtype (hi truncated, lo exact remainder)
static __device__ __forceinline__ void cvt_split(float w, unsigned short &hi, unsigned short &lo) {
#if AMODE_BF16
  unsigned u = __float_as_uint(w);
  hi = (unsigned short)(u >> 16);
  float rl = w - __uint_as_float((unsigned)hi << 16);
  lo = (unsigned short)(__float_as_uint(rl) >> 16);
#else
  _Float16 h = (_Float16)w;
  hi = __builtin_bit_cast(unsigned short, h);
  _Float16 l = (_Float16)(w - (float)h);
  lo = __builtin_bit_cast(unsigned short, l);
#endif
}

// 4 f32 states -> B operands (k = 4g+i maps directly to st[i]; no cross-lane moves)
static __device__ __forceinline__ void splitB(const float* st, s16x4 &Bh, s16x4 &Bl) {
#if AMODE_BF16
  unsigned ph0 = __builtin_amdgcn_perm(__float_as_uint(st[1]), __float_as_uint(st[0]), 0x07060302u);
  unsigned ph1 = __builtin_amdgcn_perm(__float_as_uint(st[3]), __float_as_uint(st[2]), 0x07060302u);
  float l0 = st[0] - __uint_as_float(__float_as_uint(st[0]) & 0xffff0000u);
  float l1 = st[1] - __uint_as_float(__float_as_uint(st[1]) & 0xffff0000u);
  float l2 = st[2] - __uint_as_float(__float_as_uint(st[2]) & 0xffff0000u);
  float l3 = st[3] - __uint_as_float(__float_as_uint(st[3]) & 0xffff0000u);
  unsigned pl0 = __builtin_amdgcn_perm(__float_as_uint(l1), __float_as_uint(l0), 0x07060302u);
  unsigned pl1 = __builtin_amdgcn_perm(__float_as_uint(l3), __float_as_uint(l2), 0x07060302u);
  i32x2 h; h.x = (int)ph0; h.y = (int)ph1;
  i32x2 l; l.x = (int)pl0; l.y = (int)pl1;
  Bh = __builtin_bit_cast(s16x4, h);
  Bl = __builtin_bit_cast(s16x4, l);
#else
  _Float16 h0 = (_Float16)st[0], h1 = (_Float16)st[1], h2 = (_Float16)st[2], h3 = (_Float16)st[3];
  f16x4 H = {h0, h1, h2, h3};
  f16x4 L = {(_Float16)(st[0] - (float)h0), (_Float16)(st[1] - (float)h1),
             (_Float16)(st[2] - (float)h2), (_Float16)(st[3] - (float)h3)};
  Bh = __builtin_bit_cast(s16x4, H);
  Bl = __builtin_bit_cast(s16x4, L);
#endif
}

static __device__ __forceinline__ s16x4 lo4(s16x8 v) {
  return __builtin_shufflevector(v, v, 0, 1, 2, 3);
}
static __device__ __forceinline__ s16x4 hi4(s16x8 v) {
  return __builtin_shufflevector(v, v, 4, 5, 6, 7);
}

// ---------------- prep: fuse site pairs, emit K=16 MFMA A-frags (natural layout) ------
// (byte-identical to rounds 10/12 — verified correct, absmax 0.125)
__global__ __launch_bounds__(256) void mps_prep(
    const float* __restrict__ W0, const float* __restrict__ W_left,
    const float* __restrict__ W_out, const float* __restrict__ W_right,
    const float* __restrict__ WN, const float* __restrict__ d1_w,
    const float* __restrict__ d1_b, const float* __restrict__ d2_w,
    const float* __restrict__ d2_b, unsigned short* __restrict__ ws)
{
  int bid = blockIdx.x;
  if (bid < 256) {
    int side = bid >> 7;
    int pair = bid & 127;
    __shared__ float Wa[512];     // [d*32 + p*16 + e]
    __shared__ float Wb[512];
    __shared__ float Amat[4][256]; // [i*2+j][m*16+k]
    int t = threadIdx.x;
    bool pad_a = (pair == 0);
    const float* base_a = side ? (W_right + (size_t)(255 - 2*pair) * 512)
                               : (W_left  + (size_t)(2*pair - 1) * 512);
    const float* base_b = side ? (W_right + (size_t)(254 - 2*pair) * 512)
                               : (W_left  + (size_t)(2*pair) * 512);
#pragma unroll
    for (int e = t; e < 512; e += 256) {
      float va;
      if (pad_a) { int d = e >> 5, p = (e >> 4) & 1, m = e & 15; va = (p == 0 && d == m) ? 1.f : 0.f; }
      else va = base_a[e];
      Wa[e] = va;
      Wb[e] = base_b[e];
    }
    __syncthreads();
#pragma unroll
    for (int ei = t; ei < 1024; ei += 256) {
      int ij = ei >> 8;            // i*2 + j
      int i_ = ij >> 1, j_ = ij & 1;
      int rem = ei & 255;
      int m = rem >> 4, k = rem & 15;
      float acc = 0.f;
      if (side == 0) {
#pragma unroll
        for (int tt = 0; tt < 16; ++tt) acc += Wa[k*32 + i_*16 + tt] * Wb[tt*32 + j_*16 + m];
      } else {
#pragma unroll
        for (int tt = 0; tt < 16; ++tt) acc += Wb[m*32 + j_*16 + tt] * Wa[tt*32 + i_*16 + k];
      }
      Amat[ij][m*16 + k] = acc;
    }
    __syncthreads();
    {
      int rg = t >> 6, l = t & 63;      // rg: 0=[00h|10h] 1=[01h|11h] 2=[00l|10l] 3=[01l|11l]
      int jj = rg & 1, lo = rg >> 1;
      int m = l & 15, g4 = (l >> 4) * 4;
      s16x8 v8;
#pragma unroll
      for (int i = 0; i < 4; ++i) {
        int k = g4 + i;
        unsigned short h, lw;
        cvt_split(Amat[jj][m*16 + k], h, lw);          // (i=0, j=jj)
        v8[i] = (short)(lo ? lw : h);
        cvt_split(Amat[2 + jj][m*16 + k], h, lw);      // (i=1, j=jj)
        v8[4 + i] = (short)(lo ? lw : h);
      }
      *reinterpret_cast<s16x8*>(ws + (size_t)side * WS_SIDE_STRIDE
                                   + (size_t)pair * 2048 + rg * 512 + l * 8) = v8;
    }
  } else {
    // M[d][e] = sum_o wef[o] * W_out[d][o][e];  c0 = d2_b + sum_h d2_w[h] d1_b[h]
    int t = threadIdx.x;
    int d = t >> 4, e = t & 15;
    float acc = 0.f;
#pragma unroll
    for (int o = 0; o < 8; ++o) {
      float wef = 0.f;
      for (int hh = 0; hh < 24; ++hh) wef += d2_w[hh] * d1_w[hh*8 + o];
      acc += wef * W_out[d*128 + o*16 + e];
    }
    float* wf = reinterpret_cast<float*>(ws);
    wf[262144 + t] = acc;
    if (t == 0) {
      float c0 = d2_b[0];
      for (int hh = 0; hh < 24; ++hh) c0 += d2_w[hh] * d1_b[hh];
      wf[262400] = c0;
    }
  }
}

// ---------------- main: 256 blocks x 8 waves {4L,4R}, 16 samples/wave, 2 waves/SIMD ----
// R12 structure + COMPILER-PROOF ds_read pipeline: inline-asm ds_read_b128 issues pair
// p+1's 4 reads before pair p's compute; counted s_waitcnt lgkmcnt(4) (never 0 mid-chunk)
// + sched_barrier(0) fence (rule #18) so MFMAs can't hoist above the wait. Only DS ops
// are in flight on lgkmcnt inside the loop (global_load_lds / x-loads count on vmcnt).
__global__ __launch_bounds__(512, 2) void mps_main(
    const float* __restrict__ x, const float* __restrict__ W0,
    const float* __restrict__ WN, const unsigned short* __restrict__ ws,
    float* __restrict__ out)
{
  __shared__ __align__(16) unsigned short sbuf[2][2][CHUNKP][4][64][8]; // 128 KiB
  __shared__ float fin[2][64][16];                                      // 8 KiB

  const int tidx = threadIdx.x;
  const int wave = tidx >> 6;
  const int lane = tidx & 63;
  const int side = wave >> 2;         // waves 0-3 left, 4-7 right
  const int q    = wave & 3;          // sample group
  const int n    = lane & 15;         // sample column
  const int g    = lane >> 4;         // lane group: rows/k 4g..4g+3
  const int b    = blockIdx.x * 64 + q * 16 + n;
  const float* xrow = x + (size_t)b * F_N;

  // init B: lane-group g holds v0[4g..4g+3]
  s16x4 Bh, Bl;
  float st[4];
  {
    float xi0 = side ? xrow[F_N-1] : xrow[0];
#pragma unroll
    for (int i = 0; i < 4; ++i) {
      int j = g*4 + i;
      float a0 = side ? WN[j*2]   : W0[j];
      float a1 = side ? WN[j*2+1] : W0[16+j];
      st[i] = fmaf(xi0, a1, a0);
    }
    splitB(st, Bh, Bl);
  }

  f32x4 Dz = {0.f, 0.f, 0.f, 0.f};

  // cooperative stage: 64 segments of 1 KB (2 sides x 8 pairs x 4 regions), 8 per wave
  auto stage = [&](int chunk, int db) {
#pragma unroll
    for (int s2 = 0; s2 < 8; ++s2) {
      int seg = wave * 8 + s2;
      int ss  = seg >> 5;
      int rem = seg & 31;
      int pr  = rem >> 2, rg = rem & 3;
      const unsigned short* src = ws + (size_t)ss * WS_SIDE_STRIDE
                                + (size_t)(chunk * CHUNKP + pr) * 2048 + rg * 512 + lane * 8;
      __builtin_amdgcn_global_load_lds(
        (const __attribute__((address_space(1))) void*)src,
        (__attribute__((address_space(3))) void*)(&sbuf[ss][db][pr][rg][0][0]),
        16, 0, 0);
    }
  };

  auto xbase = [&](int c) { return xrow + (side ? (496 - 16*c) : (16*c)); };

  float4 xq0, xq1, xq2, xq3;
  {
    const float* xp = xbase(0);
    xq0 = *reinterpret_cast<const float4*>(xp);
    xq1 = *reinterpret_cast<const float4*>(xp + 4);
    xq2 = *reinterpret_cast<const float4*>(xp + 8);
    xq3 = *reinterpret_cast<const float4*>(xp + 12);
  }

  stage(0, 0);
  asm volatile("s_waitcnt vmcnt(0)" ::: "memory");
  __syncthreads();

#pragma unroll 1
  for (int c = 0; c < NCHUNK; ++c) {
    float4 xn0 = xq0, xn1 = xq1, xn2 = xq2, xn3 = xq3;
    if (c + 1 < NCHUNK) {
      stage(c + 1, (c + 1) & 1);
      const float* xp = xbase(c + 1);
      xn0 = *reinterpret_cast<const float4*>(xp);
      xn1 = *reinterpret_cast<const float4*>(xp + 4);
      xn2 = *reinterpret_cast<const float4*>(xp + 8);
      xn3 = *reinterpret_cast<const float4*>(xp + 12);
    }

    // x schedule for this chunk (elem i = xbase[i])
    float xa[8], xb[8];
    {
      float e0=xq0.x, e1=xq0.y, e2=xq0.z, e3=xq0.w, e4=xq1.x, e5=xq1.y, e6=xq1.z, e7=xq1.w;
      float e8=xq2.x, e9=xq2.y, e10=xq2.z, e11=xq2.w, e12=xq3.x, e13=xq3.y, e14=xq3.z, e15=xq3.w;
      if (side == 0) {
        xa[0]=e0;  xb[0]=e1;  xa[1]=e2;  xb[1]=e3;
        xa[2]=e4;  xb[2]=e5;  xa[3]=e6;  xb[3]=e7;
        xa[4]=e8;  xb[4]=e9;  xa[5]=e10; xb[5]=e11;
        xa[6]=e12; xb[6]=e13; xa[7]=e14; xb[7]=e15;
      } else {
        xa[0]=e15; xb[0]=e14; xa[1]=e13; xb[1]=e12;
        xa[2]=e11; xb[2]=e10; xa[3]=e9;  xb[3]=e8;
        xa[4]=e7;  xb[4]=e6;  xa[5]=e5;  xb[5]=e4;
        xa[6]=e3;  xb[6]=e2;  xa[7]=e1;  xb[7]=e0;
      }
    }

    // base LDS address for this chunk's buffer (addrspace(3): 32-bit VGPR)
    lds_cptr base = (lds_cptr)(&sbuf[side][c & 1][0][0][0][0]) + (size_t)lane * 8;

    // prologue: issue pair 0's 4 reads (buffer staged + barriered last chunk)
    s16x8 r0, r1, r2, r3, m0, m1, m2, m3;
    DSR(r0, base, "0");
    DSR(r1, base, "1024");
    DSR(r2, base, "2048");
    DSR(r3, base, "3072");

#pragma unroll
    for (int pr = 0; pr < CHUNKP; ++pr) {
      // issue pair pr+1's reads, then wait only for pair pr's (4 newest stay in flight)
      if (pr + 1 < CHUNKP) {
        lds_cptr bp = base + (pr + 1) * 2048;       // 2048 shorts = 4096 B per pair
        DSR(m0, bp, "0");
        DSR(m1, bp, "1024");
        DSR(m2, bp, "2048");
        DSR(m3, bp, "3072");
        asm volatile("s_waitcnt lgkmcnt(4)" ::: "memory");
      } else {
        asm volatile("s_waitcnt lgkmcnt(0)" ::: "memory");
      }
      __builtin_amdgcn_sched_barrier(0);            // rule #18: pin MFMAs below the wait

      s16x4 a00h = lo4(r0), a10h = hi4(r0);
      s16x4 a01h = lo4(r1), a11h = hi4(r1);
      s16x4 a00l = lo4(r2), a10l = hi4(r2);
      s16x4 a01l = lo4(r3), a11l = hi4(r3);

      // 4 independent 3-deep acc chains (R12 form — chains are free, R13 showed)
      f32x4 D00 = MFMA16(a00h, Bh, Dz);
      f32x4 D10 = MFMA16(a10h, Bh, Dz);
      f32x4 D01 = MFMA16(a01h, Bh, Dz);
      f32x4 D11 = MFMA16(a11h, Bh, Dz);
      D00 = MFMA16(a00h, Bl, D00);
      D10 = MFMA16(a10h, Bl, D10);
      D01 = MFMA16(a01h, Bl, D01);
      D11 = MFMA16(a11h, Bl, D11);
      D00 = MFMA16(a00l, Bh, D00);
      D10 = MFMA16(a10l, Bh, D10);
      D01 = MFMA16(a01l, Bh, D01);
      D11 = MFMA16(a11l, Bh, D11);

      // st = (D00 + xa D10) + xb (D01 + xa D11)   (x applied in f32)
#pragma unroll
      for (int r = 0; r < 4; ++r) {
        float t0 = fmaf(xa[pr], D10[r], D00[r]);
        float t1 = fmaf(xa[pr], D11[r], D01[r]);
        st[r] = fmaf(xb[pr], t1, t0);
      }
      splitB(st, Bh, Bl);                 // D-layout == next B-layout: no cross-lane moves

      r0 = m0; r1 = m1; r2 = m2; r3 = m3;
    }
    asm volatile("s_waitcnt vmcnt(0)" ::: "memory");
    __syncthreads();
    xq0 = xn0; xq1 = xn1; xq2 = xn2; xq3 = xn3;
  }

  // final f32 state (natural rows 4g..4g+3) -> LDS
#pragma unroll
  for (int r = 0; r < 4; ++r) fin[side][q*16 + n][g*4 + r] = st[r];
  __syncthreads();

  // head: y = c0 + v^T M u, 8 threads per sample (64 samples x 8 = 512 threads)
  {
    int s = tidx >> 3, j = tidx & 7;
    const float* Mf = reinterpret_cast<const float*>(ws) + 262144;
    float c0 = reinterpret_cast<const float*>(ws)[262400];
    float acc = 0.f;
#pragma unroll
    for (int dd = 0; dd < 2; ++dd) {
      int d = j*2 + dd;
      float zd = 0.f;
#pragma unroll
      for (int e = 0; e < 16; ++e) zd = fmaf(Mf[d*16 + e], fin[1][s][e], zd);
      acc = fmaf(fin[0][s][d], zd, acc);
    }
    acc += __shfl_xor(acc, 1, 64);
    acc += __shfl_xor(acc, 2, 64);
    acc += __shfl_xor(acc, 4, 64);
    if (j == 0) out[blockIdx.x*64 + s] = acc + c0;
  }
}

extern "C" void kernel_launch(void* const* d_in, const int* in_sizes, int n_in,
                              void* d_out, int out_size, void* d_ws, size_t ws_size,
                              hipStream_t stream)
{
  const float* x       = (const float*)d_in[0];
  const float* W0      = (const float*)d_in[1];
  const float* W_left  = (const float*)d_in[2];
  const float* W_out   = (const float*)d_in[3];
  const float* W_right = (const float*)d_in[4];
  const float* WN      = (const float*)d_in[5];
  const float* d1_w    = (const float*)d_in[6];
  const float* d1_b    = (const float*)d_in[7];
  const float* d2_w    = (const float*)d_in[8];
  const float* d2_b    = (const float*)d_in[9];
  unsigned short* ws   = (unsigned short*)d_ws;
  float* out           = (float*)d_out;

  if (ws_size < (size_t)WS_BYTES_NEEDED) return;

  hipLaunchKernelGGL(mps_prep, dim3(257), dim3(256), 0, stream,
                     W0, W_left, W_out, W_right, WN, d1_w, d1_b, d2_w, d2_b, ws);
  hipLaunchKernelGGL(mps_main, dim3(B_N/64), dim3(512), 0, stream,
                     x, W0, WN, ws, out);
}